// Round 1
// baseline (320.166 us; speedup 1.0000x reference)
//
#include <hip/hip_runtime.h>
#include <math.h>

#define T_DIM 64
#define U_DIM 142
#define I_DIM 4500
#define B_DIM 16384
#define K_TOP 10

// Transposed qos layout: qt[t][i][v], v padded to PADU so each column starts
// 640B-aligned and occupies exactly 5 cachelines.
#define PADU  160
#define NT_I  71   // ceil(4500/64)
#define NT_V  3    // ceil(142/64)

// ---------------------------------------------------------------------------
// Phase 1: tiled transpose qos[T,U,I] -> qt[T,I,PADU].
// 64x64 tiles in LDS ([64][65] padding -> conflict-free), float4 global reads
// along i, 256B/wave coalesced writes along v.
// ---------------------------------------------------------------------------
__global__ __launch_bounds__(256) void transpose_kernel(
    const float* __restrict__ qos,  // [T,U,I]
    float*       __restrict__ qt)   // [T,I,PADU]
{
    __shared__ float tile[64][65];

    const int blk  = blockIdx.x;
    const int it   = blk % NT_I;
    const int rest = blk / NT_I;
    const int vt   = rest % NT_V;
    const int t    = rest / NT_V;
    const int i0   = it * 64;
    const int v0   = vt * 64;

    // Load 64(v) x 64(i) tile: each thread reads one float4 along i, 4 rounds.
    const int il = (threadIdx.x & 15) * 4;  // i offset within tile (16B aligned)
    const int vl = threadIdx.x >> 4;        // 0..15
#pragma unroll
    for (int r = 0; r < 4; ++r) {
        const int v = v0 + vl + 16 * r;
        const int i = i0 + il;
        float4 d = make_float4(0.0f, 0.0f, 0.0f, 0.0f);
        if (v < U_DIM) {
            const float* src = qos + ((size_t)t * U_DIM + v) * I_DIM + i;
            if (i + 3 < I_DIM) {
                d = *(const float4*)src;
            } else {
                if (i + 0 < I_DIM) d.x = src[0];
                if (i + 1 < I_DIM) d.y = src[1];
                if (i + 2 < I_DIM) d.z = src[2];
                if (i + 3 < I_DIM) d.w = src[3];
            }
        }
        const int vr = vl + 16 * r;
        tile[vr][il + 0] = d.x;
        tile[vr][il + 1] = d.y;
        tile[vr][il + 2] = d.z;
        tile[vr][il + 3] = d.w;
    }
    __syncthreads();

    // Store transposed: wave writes 64 consecutive v's (256B chunk) per i.
    const int wx = threadIdx.x & 63;  // v within tile
    const int wy = threadIdx.x >> 6;  // 0..3
    const int v  = v0 + wx;
    if (v < U_DIM) {
#pragma unroll
        for (int r = 0; r < 16; ++r) {
            const int i = i0 + wy + 4 * r;
            if (i < I_DIM)
                qt[((size_t)t * I_DIM + i) * PADU + v] = tile[wx][wy + 4 * r];
        }
    }
}

// ---------------------------------------------------------------------------
// Phase 2: one wave per batch element, column reads now fully coalesced
// (142 contiguous floats). Top-10 via iterative max-extraction with a
// lightweight (val,idx) butterfly; winner's contribution recovered with a
// single post-reduce shuffle. Tie-break toward lower user index (identical
// ordering semantics to the proven baseline kernel).
// ---------------------------------------------------------------------------
__global__ __launch_bounds__(256) void ucf_kernel_t(
    const float* __restrict__ qt,        // [T,I,PADU]
    const float* __restrict__ user_avg,  // [T,U]
    const float* __restrict__ user_sim,  // [U,U]
    const int*   __restrict__ user_id,   // [B]
    const int*   __restrict__ item_id,   // [B]
    const int*   __restrict__ time_id,   // [B]
    float*       __restrict__ out)       // [B]
{
    const int lane = threadIdx.x & 63;
    const int wid  = threadIdx.x >> 6;
    const int b    = blockIdx.x * 4 + wid;
    if (b >= B_DIM) return;

    const int u = user_id[b];
    const int i = item_id[b];
    const int t = time_id[b];

    const float* qcol = qt + ((size_t)t * I_DIM + i) * PADU;  // contiguous in v
    const float* srow = user_sim + (size_t)u * U_DIM;
    const float* arow = user_avg + (size_t)t * U_DIM;

    float val0 = -INFINITY, val1 = -INFINITY, val2 = -INFINITY;
    float con0 = 0.0f, con1 = 0.0f, con2 = 0.0f;
    {
        const int v0 = lane;
        const int v1 = lane + 64;
        const int v2 = lane + 128;
        // v0, v1 always in range (U_DIM = 142 > 127)
        const float rv0 = qcol[v0];
        const float rv1 = qcol[v1];
        const float a0  = arow[v0];
        const float a1  = arow[v1];
        const float s0  = srow[v0];
        const float s1  = srow[v1];
        val0 = (rv0 > 0.0f) ? s0 : 0.0f;
        con0 = val0 * (rv0 - a0);
        val1 = (rv1 > 0.0f) ? s1 : 0.0f;
        con1 = val1 * (rv1 - a1);
        if (v2 < U_DIM) {
            const float rv2 = qcol[v2];
            const float a2  = arow[v2];
            const float s2  = srow[v2];
            val2 = (rv2 > 0.0f) ? s2 : 0.0f;
            con2 = val2 * (rv2 - a2);
        }
    }

    float ssum = 0.0f;  // sum of top-k sims
    float wsum = 0.0f;  // sum of top-k sim*(r-avg)
#pragma unroll
    for (int k = 0; k < K_TOP; ++k) {
        // local argmax over 3 slots (strict > keeps lower v on tie)
        float mv = val0; int mk = lane;
        if (val1 > mv) { mv = val1; mk = lane + 64; }
        if (val2 > mv) { mv = val2; mk = lane + 128; }
        // wave butterfly max-reduce on (val, idx); all lanes converge
#pragma unroll
        for (int off = 32; off > 0; off >>= 1) {
            const float ov = __shfl_xor(mv, off, 64);
            const int   ok = __shfl_xor(mk, off, 64);
            if (ov > mv || (ov == mv && ok < mk)) { mv = ov; mk = ok; }
        }
        // recover winner's contribution with one shuffle (mk uniform here)
        const int slot = mk >> 6;
        const int wl   = mk & 63;
        const float csel = (slot == 0) ? con0 : (slot == 1) ? con1 : con2;
        const float mc = __shfl(csel, wl, 64);
        ssum += mv;
        wsum += mc;
        // winner's owner lane removes it from candidacy
        if (wl == lane) {
            if (slot == 0)      val0 = -INFINITY;
            else if (slot == 1) val1 = -INFINITY;
            else                val2 = -INFINITY;
        }
    }

    if (lane == 0) {
        const float avg_u = arow[u];
        out[b] = avg_u + wsum / (ssum + 1e-8f);
    }
}

// ---------------------------------------------------------------------------
// Fallback (proven baseline): direct scattered gather, used only if the
// workspace is too small for the transposed copy.
// ---------------------------------------------------------------------------
__global__ __launch_bounds__(256) void ucf_kernel(
    const float* __restrict__ qos,       // [T,U,I]
    const float* __restrict__ user_avg,  // [T,U]
    const float* __restrict__ user_sim,  // [U,U]
    const int*   __restrict__ user_id,   // [B]
    const int*   __restrict__ item_id,   // [B]
    const int*   __restrict__ time_id,   // [B]
    float*       __restrict__ out)       // [B]
{
    const int lane = threadIdx.x & 63;
    const int wid  = threadIdx.x >> 6;
    const int b    = blockIdx.x * 4 + wid;
    if (b >= B_DIM) return;

    const int u = user_id[b];
    const int i = item_id[b];
    const int t = time_id[b];

    const float* qcol = qos + ((size_t)t * U_DIM) * (size_t)I_DIM + i;
    const float* srow = user_sim + (size_t)u * U_DIM;
    const float* arow = user_avg + (size_t)t * U_DIM;

    float val[3];
    float con[3];
#pragma unroll
    for (int j = 0; j < 3; ++j) {
        const int v = lane + j * 64;
        float sv = -INFINITY;
        float cv = 0.0f;
        if (v < U_DIM) {
            const float rv = qcol[(size_t)v * I_DIM];
            const float av = arow[v];
            const float s  = srow[v];
            sv = (rv > 0.0f) ? s : 0.0f;
            cv = sv * (rv - av);
        }
        val[j] = sv;
        con[j] = cv;
    }

    float ssum = 0.0f;
    float wsum = 0.0f;
#pragma unroll
    for (int k = 0; k < K_TOP; ++k) {
        float mv = val[0]; float mc = con[0]; int mk = lane;
        if (val[1] > mv) { mv = val[1]; mc = con[1]; mk = lane + 64; }
        if (val[2] > mv) { mv = val[2]; mc = con[2]; mk = lane + 128; }
#pragma unroll
        for (int off = 32; off > 0; off >>= 1) {
            const float ov = __shfl_xor(mv, off, 64);
            const float oc = __shfl_xor(mc, off, 64);
            const int   ok = __shfl_xor(mk, off, 64);
            if (ov > mv || (ov == mv && ok < mk)) { mv = ov; mc = oc; mk = ok; }
        }
        ssum += mv;
        wsum += mc;
        if ((mk & 63) == lane) {
            const int slot = mk >> 6;
            if (slot == 0)      val[0] = -INFINITY;
            else if (slot == 1) val[1] = -INFINITY;
            else                val[2] = -INFINITY;
        }
    }

    if (lane == 0) {
        const float avg_u = arow[u];
        out[b] = avg_u + wsum / (ssum + 1e-8f);
    }
}

extern "C" void kernel_launch(void* const* d_in, const int* in_sizes, int n_in,
                              void* d_out, int out_size, void* d_ws, size_t ws_size,
                              hipStream_t stream) {
    const float* qos  = (const float*)d_in[0];
    const float* uavg = (const float*)d_in[1];
    const float* usim = (const float*)d_in[2];
    const int*   uid  = (const int*)d_in[3];
    const int*   iid  = (const int*)d_in[4];
    const int*   tid  = (const int*)d_in[5];
    // d_in[6] is top_k, fixed at 10 by the problem instance (K_TOP).
    float* out = (float*)d_out;

    const size_t qt_bytes = (size_t)T_DIM * I_DIM * PADU * sizeof(float); // ~184.3 MB

    if (d_ws != nullptr && ws_size >= qt_bytes) {
        float* qt = (float*)d_ws;
        transpose_kernel<<<dim3(T_DIM * NT_V * NT_I), dim3(256), 0, stream>>>(qos, qt);
        ucf_kernel_t<<<dim3(B_DIM / 4), dim3(256), 0, stream>>>(
            qt, uavg, usim, uid, iid, tid, out);
    } else {
        // workspace too small: proven direct-gather path
        ucf_kernel<<<dim3(B_DIM / 4), dim3(256), 0, stream>>>(
            qos, uavg, usim, uid, iid, tid, out);
    }
}

// Round 2
// 273.300 us; speedup vs baseline: 1.1715x; 1.1715x over previous
//
#include <hip/hip_runtime.h>
#include <math.h>

#define T_DIM 64
#define U_DIM 142
#define I_DIM 4500
#define B_DIM 16384
#define K_TOP 10

// t-binning geometry: CAP slots per t (pow2 so slot->t is a shift).
// Mean occupancy = B/T = 256, CAP = 512 = mean + 16 sigma; overflow region of
// B slots guarantees correctness for ANY tid distribution.
#define CAP    512
#define TSLOTS (T_DIM * CAP)          // 32768
#define SLOTS  (TSLOTS + B_DIM)       // 49152
#define NBLK   (SLOTS / 4)            // 12288 blocks (4 waves each)
#define NXCD   8
#define CHUNK  (NBLK / NXCD)          // 1536 — divisible, swizzle bijective

// Workspace layout:
//   hdr[0..63]  = per-t counters, hdr[64] = overflow counter  (ints)
//   perm[SLOTS] = batch index per slot (valid iff within counts)
#define HDR_INTS  72                  // padded
#define WS_BYTES  ((HDR_INTS + SLOTS) * sizeof(int))

// ---------------------------------------------------------------------------
// Phase 0: zero the counters (tiny kernel; avoids hipMemsetAsync entirely).
// ---------------------------------------------------------------------------
__global__ void zero_hdr(int* __restrict__ hdr)
{
    if (threadIdx.x < HDR_INTS) hdr[threadIdx.x] = 0;
}

// ---------------------------------------------------------------------------
// Phase 1: bin batch indices by t via atomic cursors. Order within a bin is
// nondeterministic but irrelevant: each batch writes only its own out[b].
// ---------------------------------------------------------------------------
__global__ __launch_bounds__(256) void build_perm(
    const int* __restrict__ time_id,  // [B]
    int*       __restrict__ hdr,      // [HDR_INTS]
    int*       __restrict__ perm)     // [SLOTS]
{
    const int b = blockIdx.x * 256 + threadIdx.x;
    if (b >= B_DIM) return;
    const int t = time_id[b];
    const int j = atomicAdd(&hdr[t], 1);
    int slot;
    if (j < CAP) slot = t * CAP + j;
    else         slot = TSLOTS + atomicAdd(&hdr[64], 1);  // overflow (never in practice)
    perm[slot] = b;
}

// ---------------------------------------------------------------------------
// Phase 2: one wave per occupied slot. Slots of one t are contiguous, and the
// XCD-chunk swizzle puts each t-group on ONE XCD so its ~1.5 MB of unique
// qos lines stays L2-resident across the ~64 co-resident blocks that share it.
// Top-10: 3-slot local argmax + (val,idx) butterfly; winner's contribution
// recovered with one post-reduce shuffle (verified bit-exact in round 1).
// ---------------------------------------------------------------------------
__global__ __launch_bounds__(256) void ucf_main(
    const float* __restrict__ qos,       // [T,U,I]
    const float* __restrict__ user_avg,  // [T,U]
    const float* __restrict__ user_sim,  // [U,U]
    const int*   __restrict__ user_id,   // [B]
    const int*   __restrict__ item_id,   // [B]
    const int*   __restrict__ hdr,       // [HDR_INTS]
    const int*   __restrict__ perm,      // [SLOTS]
    float*       __restrict__ out)       // [B]
{
    const int lane = threadIdx.x & 63;
    const int wid  = threadIdx.x >> 6;

    // bijective XCD-chunk swizzle: hardware bid%8 = XCD; logical chunk k -> XCD k
    const int bid  = blockIdx.x;
    const int lblk = (bid % NXCD) * CHUNK + bid / NXCD;
    const int slot = lblk * 4 + wid;

    // slot -> batch index (or exit if slot unoccupied)
    int b = -1;
    if (slot < TSLOTS) {
        const int t_ = slot >> 9;           // CAP = 512
        const int j  = slot & (CAP - 1);
        int c = hdr[t_];
        if (c > CAP) c = CAP;
        if (j < c) b = perm[slot];
    } else {
        const int k = slot - TSLOTS;
        if (k < hdr[64]) b = perm[slot];
    }
    if (b < 0) return;

    const int u = user_id[b];
    const int i = item_id[b];
    const int t = slot < TSLOTS ? (slot >> 9) : 0;   // recompute below if overflow
    // For overflow slots t must come from memory (rare path): reload safely.
    const float* qcol;
    const float* arow;
    {
        int tt = t;
        if (slot >= TSLOTS) {
            // overflow: derive t from the batch's own row in perm-source data.
            // (read back via user_avg-indexing is impossible; store tid read)
            // We simply re-read time_id through user_id pointer arithmetic is
            // not possible -> keep a safe global read:
            tt = __ldg(((const int*)hdr) + 0) * 0;  // placeholder, replaced below
        }
        (void)tt;
        qcol = nullptr; arow = nullptr;
    }
    // --- the above overflow reconstruction is dead weight; do it simply: ---
    int treal;
    if (slot < TSLOTS) treal = slot >> 9;
    else               treal = -1;  // fetch from time_id is required
    if (treal < 0) {
        // Overflow path (statistically never taken): we need time_id[b].
        // time_id not passed to keep arg count; derive via hdr? Not possible.
        // -> handled by passing time_id; see parameter below.
        treal = 0;
    }
    (void)treal;

    // NOTE: to keep the overflow path exactly correct we pass time_id too.
    // (Compiler removes the dead code above.)
    out += 0;  // no-op

    // real implementation continues in ucf_main2 below
}

// Clean implementation (the one actually launched): includes time_id so the
// overflow path is exactly correct.
__global__ __launch_bounds__(256) void ucf_main2(
    const float* __restrict__ qos,       // [T,U,I]
    const float* __restrict__ user_avg,  // [T,U]
    const float* __restrict__ user_sim,  // [U,U]
    const int*   __restrict__ user_id,   // [B]
    const int*   __restrict__ item_id,   // [B]
    const int*   __restrict__ time_id,   // [B]
    const int*   __restrict__ hdr,       // [HDR_INTS]
    const int*   __restrict__ perm,      // [SLOTS]
    float*       __restrict__ out)       // [B]
{
    const int lane = threadIdx.x & 63;
    const int wid  = threadIdx.x >> 6;

    const int bid  = blockIdx.x;
    const int lblk = (bid % NXCD) * CHUNK + bid / NXCD;
    const int slot = lblk * 4 + wid;

    int b = -1;
    if (slot < TSLOTS) {
        const int t_ = slot >> 9;           // CAP = 512
        const int j  = slot & (CAP - 1);
        int c = hdr[t_];
        if (c > CAP) c = CAP;
        if (j < c) b = perm[slot];
    } else {
        const int k = slot - TSLOTS;
        if (k < hdr[64]) b = perm[slot];
    }
    if (b < 0) return;

    const int u = user_id[b];
    const int i = item_id[b];
    const int t = (slot < TSLOTS) ? (slot >> 9) : time_id[b];

    const float* qcol = qos + ((size_t)t * U_DIM) * (size_t)I_DIM + i; // qcol[v*I]
    const float* srow = user_sim + (size_t)u * U_DIM;
    const float* arow = user_avg + (size_t)t * U_DIM;

    float val0 = -INFINITY, val1 = -INFINITY, val2 = -INFINITY;
    float con0 = 0.0f, con1 = 0.0f, con2 = 0.0f;
    {
        const int v0 = lane;
        const int v1 = lane + 64;
        const int v2 = lane + 128;
        const float rv0 = qcol[(size_t)v0 * I_DIM];
        const float rv1 = qcol[(size_t)v1 * I_DIM];
        const float a0  = arow[v0];
        const float a1  = arow[v1];
        const float s0  = srow[v0];
        const float s1  = srow[v1];
        val0 = (rv0 > 0.0f) ? s0 : 0.0f;
        con0 = val0 * (rv0 - a0);
        val1 = (rv1 > 0.0f) ? s1 : 0.0f;
        con1 = val1 * (rv1 - a1);
        if (v2 < U_DIM) {
            const float rv2 = qcol[(size_t)v2 * I_DIM];
            const float a2  = arow[v2];
            const float s2  = srow[v2];
            val2 = (rv2 > 0.0f) ? s2 : 0.0f;
            con2 = val2 * (rv2 - a2);
        }
    }

    float ssum = 0.0f;  // sum of top-k sims
    float wsum = 0.0f;  // sum of top-k sim*(r-avg)
#pragma unroll
    for (int k = 0; k < K_TOP; ++k) {
        // local argmax over 3 slots (ascending v, strict > keeps lower v on tie)
        float mv = val0; int mk = lane;
        if (val1 > mv) { mv = val1; mk = lane + 64; }
        if (val2 > mv) { mv = val2; mk = lane + 128; }
        // wave butterfly max-reduce on (val, idx); tie -> lower user index
#pragma unroll
        for (int off = 32; off > 0; off >>= 1) {
            const float ov = __shfl_xor(mv, off, 64);
            const int   ok = __shfl_xor(mk, off, 64);
            if (ov > mv || (ov == mv && ok < mk)) { mv = ov; mk = ok; }
        }
        // recover winner's contribution with one shuffle (mk uniform by now)
        const int sl = mk >> 6;
        const int wl = mk & 63;
        const float csel = (sl == 0) ? con0 : (sl == 1) ? con1 : con2;
        const float mc = __shfl(csel, wl, 64);
        ssum += mv;
        wsum += mc;
        // winner's owner lane removes it from candidacy
        if (wl == lane) {
            if (sl == 0)      val0 = -INFINITY;
            else if (sl == 1) val1 = -INFINITY;
            else              val2 = -INFINITY;
        }
    }

    if (lane == 0) {
        const float avg_u = arow[u];
        out[b] = avg_u + wsum / (ssum + 1e-8f);
    }
}

// ---------------------------------------------------------------------------
// Fallback (proven round-0 baseline): used only if workspace is too small.
// ---------------------------------------------------------------------------
__global__ __launch_bounds__(256) void ucf_kernel(
    const float* __restrict__ qos,
    const float* __restrict__ user_avg,
    const float* __restrict__ user_sim,
    const int*   __restrict__ user_id,
    const int*   __restrict__ item_id,
    const int*   __restrict__ time_id,
    float*       __restrict__ out)
{
    const int lane = threadIdx.x & 63;
    const int wid  = threadIdx.x >> 6;
    const int b    = blockIdx.x * 4 + wid;
    if (b >= B_DIM) return;

    const int u = user_id[b];
    const int i = item_id[b];
    const int t = time_id[b];

    const float* qcol = qos + ((size_t)t * U_DIM) * (size_t)I_DIM + i;
    const float* srow = user_sim + (size_t)u * U_DIM;
    const float* arow = user_avg + (size_t)t * U_DIM;

    float val[3];
    float con[3];
#pragma unroll
    for (int j = 0; j < 3; ++j) {
        const int v = lane + j * 64;
        float sv = -INFINITY;
        float cv = 0.0f;
        if (v < U_DIM) {
            const float rv = qcol[(size_t)v * I_DIM];
            const float av = arow[v];
            const float s  = srow[v];
            sv = (rv > 0.0f) ? s : 0.0f;
            cv = sv * (rv - av);
        }
        val[j] = sv;
        con[j] = cv;
    }

    float ssum = 0.0f;
    float wsum = 0.0f;
#pragma unroll
    for (int k = 0; k < K_TOP; ++k) {
        float mv = val[0]; float mc = con[0]; int mk = lane;
        if (val[1] > mv) { mv = val[1]; mc = con[1]; mk = lane + 64; }
        if (val[2] > mv) { mv = val[2]; mc = con[2]; mk = lane + 128; }
#pragma unroll
        for (int off = 32; off > 0; off >>= 1) {
            const float ov = __shfl_xor(mv, off, 64);
            const float oc = __shfl_xor(mc, off, 64);
            const int   ok = __shfl_xor(mk, off, 64);
            if (ov > mv || (ov == mv && ok < mk)) { mv = ov; mc = oc; mk = ok; }
        }
        ssum += mv;
        wsum += mc;
        if ((mk & 63) == lane) {
            const int slot = mk >> 6;
            if (slot == 0)      val[0] = -INFINITY;
            else if (slot == 1) val[1] = -INFINITY;
            else                val[2] = -INFINITY;
        }
    }

    if (lane == 0) {
        const float avg_u = arow[u];
        out[b] = avg_u + wsum / (ssum + 1e-8f);
    }
}

extern "C" void kernel_launch(void* const* d_in, const int* in_sizes, int n_in,
                              void* d_out, int out_size, void* d_ws, size_t ws_size,
                              hipStream_t stream) {
    const float* qos  = (const float*)d_in[0];
    const float* uavg = (const float*)d_in[1];
    const float* usim = (const float*)d_in[2];
    const int*   uid  = (const int*)d_in[3];
    const int*   iid  = (const int*)d_in[4];
    const int*   tid  = (const int*)d_in[5];
    // d_in[6] is top_k, fixed at 10 by the problem instance (K_TOP).
    float* out = (float*)d_out;

    if (d_ws != nullptr && ws_size >= WS_BYTES) {
        int* hdr  = (int*)d_ws;
        int* perm = hdr + HDR_INTS;
        zero_hdr<<<dim3(1), dim3(128), 0, stream>>>(hdr);
        build_perm<<<dim3((B_DIM + 255) / 256), dim3(256), 0, stream>>>(tid, hdr, perm);
        ucf_main2<<<dim3(NBLK), dim3(256), 0, stream>>>(
            qos, uavg, usim, uid, iid, tid, hdr, perm, out);
    } else {
        ucf_kernel<<<dim3(B_DIM / 4), dim3(256), 0, stream>>>(
            qos, uavg, usim, uid, iid, tid, out);
    }
}